// Round 3
// baseline (1891.935 us; speedup 1.0000x reference)
//
#include <hip/hip_runtime.h>
#include <float.h>

#define TPB 256
#define PG 90
#define PG2 8100
#define PG3 729000
#define DA 88
#define DA2 7744
#define DA3 681472
#define DB 84
#define DB2 7056
#define DB3 592704
#define FTOT 9483264   // 16*84^3
#define LEAKC 0.333f
#define NBF 1120       // blocks for final reduction
#define C1Z 22         // 88/4 z-groups for conv1
#define C2Z 21         // 84/4 z-groups for conv2

static __device__ __forceinline__ void atomicMaxF(float* addr, float val) {
    if (val >= 0.f) atomicMax((int*)addr, __float_as_int(val));
    else            atomicMin((unsigned int*)addr, __float_as_uint(val));
}

// hp[Np*16]: channels 0..3 = -FLT_MAX (segment_max identity), 4..15 = 0 (pad)
__global__ void k_hp_init(float* hp, int n16) {
    int t = blockIdx.x * TPB + threadIdx.x;
    if (t < n16) hp[t] = ((t & 15) < 4) ? -FLT_MAX : 0.f;
}

// weight permutes: W[o][tap] -> Wp[tap][o]  (uniform-address friendly)
__global__ void k_permW(const float* __restrict__ W, float* __restrict__ Wp, int ntap) {
    int t = blockIdx.x * TPB + threadIdx.x;
    if (t >= ntap * 16) return;
    int o = t & 15, tap = t >> 4;
    Wp[t] = W[o * ntap + tap];
}

// subconv f=2: x[N,1] * W1[8,1,16] scatter
__global__ void k_sub1(const float* __restrict__ x, const float* __restrict__ W,
                       const int* __restrict__ rin, const int* __restrict__ rout,
                       const int* __restrict__ rk, float* __restrict__ y, int P) {
    int t = blockIdx.x * TPB + threadIdx.x;
    if (t >= P * 16) return;
    int p = t >> 4, d = t & 15;
    atomicAdd(&y[rout[p] * 16 + d], x[rin[p]] * W[rk[p] * 16 + d]);
}

// generic 16->16 subconv scatter: W[k][c][d]
__global__ void k_sub16(const float* __restrict__ h, const float* __restrict__ W,
                        const int* __restrict__ rin, const int* __restrict__ rout,
                        const int* __restrict__ rk, float* __restrict__ y, int P) {
    int t = blockIdx.x * TPB + threadIdx.x;
    if (t >= P * 16) return;
    int p = t >> 4, d = t & 15;
    const float* hr = h + rin[p] * 16;
    const float* w  = W + rk[p] * 256 + d;
    float acc = 0.f;
#pragma unroll
    for (int c = 0; c < 16; c++) acc = fmaf(hr[c], w[c * 16], acc);
    atomicAdd(&y[rout[p] * 16 + d], acc);
}

// 16->16 subconv with fused BN+ReLU on the input (resnet blocks)
__global__ void k_sub16bn(const float* __restrict__ h, const float* __restrict__ g,
                          const float* __restrict__ b, const float* __restrict__ W,
                          const int* __restrict__ rin, const int* __restrict__ rout,
                          const int* __restrict__ rk, float* __restrict__ y, int P) {
    int t = blockIdx.x * TPB + threadIdx.x;
    if (t >= P * 16) return;
    int p = t >> 4, d = t & 15;
    const float* hr = h + rin[p] * 16;
    const float* w  = W + rk[p] * 256 + d;
    float acc = 0.f;
#pragma unroll
    for (int c = 0; c < 16; c++) {
        float u = fmaxf(fmaf(hr[c], g[c], b[c]), 0.f);
        acc = fmaf(u, w[c * 16], acc);
    }
    atomicAdd(&y[rout[p] * 16 + d], acc);
}

// subconv f=5: 16->4, W3[k][c][d] d<4
__global__ void k_sub3(const float* __restrict__ h, const float* __restrict__ W,
                       const int* __restrict__ rin, const int* __restrict__ rout,
                       const int* __restrict__ rk, float* __restrict__ y, int P) {
    int t = blockIdx.x * TPB + threadIdx.x;
    if (t >= P * 4) return;
    int p = t >> 2, d = t & 3;
    const float* hr = h + rin[p] * 16;
    const float* w  = W + rk[p] * 64 + d;
    float acc = 0.f;
#pragma unroll
    for (int c = 0; c < 16; c++) acc = fmaf(hr[c], w[c * 4], acc);
    atomicAdd(&y[rout[p] * 4 + d], acc);
}

// sparse max-pool: scatter-max h3[N,4] into hp[Np,16] (channels 0..3)
__global__ void k_pool(const float* __restrict__ h3, const int* __restrict__ seg,
                       float* __restrict__ hp, int N) {
    int t = blockIdx.x * TPB + threadIdx.x;
    if (t >= N * 4) return;
    int p = t >> 2, d = t & 3;
    atomicMaxF(&hp[seg[p] * 16 + d], h3[t]);
}

// h_new = w + shortcut(h);  also zero v,w for the next block's scatters
__global__ void k_resup(const float* __restrict__ cur, float* __restrict__ wbuf,
                        float* __restrict__ vbuf, const float* __restrict__ Ws,
                        float* __restrict__ nxt, int n16) {
    int t = blockIdx.x * TPB + threadIdx.x;
    if (t >= n16) return;
    int p = t >> 4, d = t & 15;
    float sc;
    if (Ws != nullptr) {
        const float* row = cur + p * 16;
        float acc = 0.f;
#pragma unroll
        for (int c = 0; c < 16; c++) acc = fmaf(row[c], Ws[c * 16 + d], acc);
        sc = acc;
    } else {
        sc = cur[t];
    }
    nxt[t] = wbuf[t] + sc;
    wbuf[t] = 0.f;
    vbuf[t] = 0.f;
}

// trailing BN+ReLU then scatter to dense grid + occupancy
__global__ void k_scatter(const float* __restrict__ h, const float* __restrict__ gf,
                          const float* __restrict__ bf, const int* __restrict__ px,
                          const int* __restrict__ py, const int* __restrict__ pz,
                          float* __restrict__ dense, unsigned char* __restrict__ occ, int n16) {
    int t = blockIdx.x * TPB + threadIdx.x;
    if (t >= n16) return;
    int p = t >> 4, c = t & 15;
    float v = fmaxf(fmaf(h[t], gf[c], bf[c]), 0.f);
    int pos = (px[p] * PG + py[p]) * PG + pz[p];
    dense[c * PG3 + pos] = v;
    if (c == 0) occ[pos] = 1;
}

// dense conv 3^3, 16->16, 90^3 -> 88^3.  No LDS: weights read via uniform
// addresses from pre-permuted Wp[tap][16] -> s_load / broadcast L1 path.
// Each thread: 4 voxels (z) x 8 outs (o-half selected by slow grid dim).
__global__ __launch_bounds__(TPB) void k_conv1(const float* __restrict__ in,
                                               const float* __restrict__ Wp,
                                               float* __restrict__ out) {
    int idx = blockIdx.x * TPB + threadIdx.x;
    if (idx >= DA2 * C1Z * 2) return;
    int oh   = idx / (DA2 * C1Z);        // output-channel half
    int idx2 = idx % (DA2 * C1Z);
    int zg = idx2 % C1Z;
    int y  = (idx2 / C1Z) % DA;
    int x  = idx2 / (C1Z * DA);
    int z0 = zg * 4;
    float acc[4][8];
#pragma unroll
    for (int vz = 0; vz < 4; vz++)
#pragma unroll
        for (int o = 0; o < 8; o++) acc[vz][o] = 0.f;
    const float* wbase = Wp + oh * 8;
    for (int ci = 0; ci < 16; ci++) {
        const float* ip = in + (size_t)ci * PG3 + x * PG2 + y * PG + z0;
        const float* wc = wbase + ci * 27 * 16;
        for (int kd = 0; kd < 3; kd++) {
            for (int kh = 0; kh < 3; kh++) {
                const float* row = ip + kd * PG2 + kh * PG;
                float4 fa = *(const float4*)row;
                float4 fb = *(const float4*)(row + 4);
                float v[8] = {fa.x, fa.y, fa.z, fa.w, fb.x, fb.y, fb.z, fb.w};
                const float* wr = wc + (kd * 9 + kh * 3) * 16;
#pragma unroll
                for (int kw = 0; kw < 3; kw++) {
                    float4 w0 = *(const float4*)(wr + kw * 16);
                    float4 w1 = *(const float4*)(wr + kw * 16 + 4);
#pragma unroll
                    for (int vz = 0; vz < 4; vz++) {
                        float val = v[kw + vz];
                        acc[vz][0] = fmaf(val, w0.x, acc[vz][0]);
                        acc[vz][1] = fmaf(val, w0.y, acc[vz][1]);
                        acc[vz][2] = fmaf(val, w0.z, acc[vz][2]);
                        acc[vz][3] = fmaf(val, w0.w, acc[vz][3]);
                        acc[vz][4] = fmaf(val, w1.x, acc[vz][4]);
                        acc[vz][5] = fmaf(val, w1.y, acc[vz][5]);
                        acc[vz][6] = fmaf(val, w1.z, acc[vz][6]);
                        acc[vz][7] = fmaf(val, w1.w, acc[vz][7]);
                    }
                }
            }
        }
    }
    int base = x * DA2 + y * DA + z0;
#pragma unroll
    for (int o = 0; o < 8; o++) {
        float4 st = {acc[0][o], acc[1][o], acc[2][o], acc[3][o]};
        *(float4*)(out + (size_t)(oh * 8 + o) * DA3 + base) = st;
    }
}

// dense conv 5^3, 16->16, 88^3 -> 84^3.  Same no-LDS uniform-weight scheme.
__global__ __launch_bounds__(TPB) void k_conv2(const float* __restrict__ in,
                                               const float* __restrict__ Wp,
                                               float* __restrict__ out) {
    int idx = blockIdx.x * TPB + threadIdx.x;
    if (idx >= DB2 * C2Z * 2) return;
    int oh   = idx / (DB2 * C2Z);
    int idx2 = idx % (DB2 * C2Z);
    int zg = idx2 % C2Z;
    int y  = (idx2 / C2Z) % DB;
    int x  = idx2 / (C2Z * DB);
    int z0 = zg * 4;
    float acc[4][8];
#pragma unroll
    for (int vz = 0; vz < 4; vz++)
#pragma unroll
        for (int o = 0; o < 8; o++) acc[vz][o] = 0.f;
    const float* wbase = Wp + oh * 8;
    for (int ci = 0; ci < 16; ci++) {
        const float* ip = in + (size_t)ci * DA3 + x * DA2 + y * DA + z0;
        const float* wc = wbase + ci * 125 * 16;
        for (int kd = 0; kd < 5; kd++) {
            for (int kh = 0; kh < 5; kh++) {
                const float* row = ip + kd * DA2 + kh * DA;
                float4 fa = *(const float4*)row;
                float4 fb = *(const float4*)(row + 4);
                float v[8] = {fa.x, fa.y, fa.z, fa.w, fb.x, fb.y, fb.z, fb.w};
                const float* wr = wc + (kd * 25 + kh * 5) * 16;
#pragma unroll
                for (int kw = 0; kw < 5; kw++) {
                    float4 w0 = *(const float4*)(wr + kw * 16);
                    float4 w1 = *(const float4*)(wr + kw * 16 + 4);
#pragma unroll
                    for (int vz = 0; vz < 4; vz++) {
                        float val = v[kw + vz];
                        acc[vz][0] = fmaf(val, w0.x, acc[vz][0]);
                        acc[vz][1] = fmaf(val, w0.y, acc[vz][1]);
                        acc[vz][2] = fmaf(val, w0.z, acc[vz][2]);
                        acc[vz][3] = fmaf(val, w0.w, acc[vz][3]);
                        acc[vz][4] = fmaf(val, w1.x, acc[vz][4]);
                        acc[vz][5] = fmaf(val, w1.y, acc[vz][5]);
                        acc[vz][6] = fmaf(val, w1.z, acc[vz][6]);
                        acc[vz][7] = fmaf(val, w1.w, acc[vz][7]);
                    }
                }
            }
        }
    }
    int base = x * DB2 + y * DB + z0;
#pragma unroll
    for (int o = 0; o < 8; o++) {
        float4 st = {acc[0][o], acc[1][o], acc[2][o], acc[3][o]};
        *(float4*)(out + (size_t)(oh * 8 + o) * DB3 + base) = st;
    }
}

// separable 7-wide box dilation of occupancy: z, then y, then x
__global__ void k_mask1(const unsigned char* __restrict__ occ, unsigned char* __restrict__ m1) {
    int t = blockIdx.x * TPB + threadIdx.x;
    if (t >= PG * PG * DB) return;
    int z = t % DB;
    int xy = t / DB;
    const unsigned char* p = occ + xy * PG + z;
    unsigned char m = 0;
#pragma unroll
    for (int k = 0; k < 7; k++) m |= p[k];
    m1[t] = m;
}
__global__ void k_mask2(const unsigned char* __restrict__ m1, unsigned char* __restrict__ m2) {
    int t = blockIdx.x * TPB + threadIdx.x;
    if (t >= PG * DB * DB) return;
    int z = t % DB;
    int y = (t / DB) % DB;
    int x = t / (DB * DB);
    unsigned char m = 0;
#pragma unroll
    for (int k = 0; k < 7; k++) m |= m1[(x * PG + y + k) * DB + z];
    m2[t] = m;
}
__global__ void k_mask3(const unsigned char* __restrict__ m2, unsigned char* __restrict__ mask) {
    int t = blockIdx.x * TPB + threadIdx.x;
    if (t >= DB3) return;
    int z = t % DB;
    int y = (t / DB) % DB;
    int x = t / DB2;
    unsigned char m = 0;
#pragma unroll
    for (int k = 0; k < 7; k++) m |= m2[((x + k) * DB + y) * DB + z];
    mask[t] = m;
}

// fused BN + leaky + mask + 10-way dot with W_lin1 rows; per-block partials to buf
__global__ __launch_bounds__(TPB) void k_final(const float* __restrict__ c2,
                                               const unsigned char* __restrict__ mask,
                                               const float* __restrict__ gbn,
                                               const float* __restrict__ bbn,
                                               const float* __restrict__ Wl1,
                                               float* __restrict__ buf) {
    int tid0 = blockIdx.x * TPB + threadIdx.x;
    int stride = gridDim.x * TPB;
    float part[10];
#pragma unroll
    for (int j = 0; j < 10; j++) part[j] = 0.f;
    for (int c = 0; c < 16; c++) {
        float g = gbn[c], b = bbn[c];
        const float* cc = c2 + (size_t)c * DB3;
        const float* wb = Wl1 + (size_t)c * DB3;
        for (int sp = tid0; sp < DB3; sp += stride) {
            float v = fmaf(cc[sp], g, b);
            v = v > 0.f ? v : LEAKC * v;
            if (mask[sp]) {
#pragma unroll
                for (int j = 0; j < 10; j++)
                    part[j] = fmaf(v, wb[(size_t)j * FTOT + sp], part[j]);
            }
        }
    }
    int lane = threadIdx.x & 63, wv = threadIdx.x >> 6;
    __shared__ float red[4][10];
#pragma unroll
    for (int j = 0; j < 10; j++) {
        float s = part[j];
#pragma unroll
        for (int off = 32; off; off >>= 1) s += __shfl_down(s, off);
        if (lane == 0) red[wv][j] = s;
    }
    __syncthreads();
    if (threadIdx.x < 10)
        buf[blockIdx.x * 10 + threadIdx.x] =
            red[0][threadIdx.x] + red[1][threadIdx.x] + red[2][threadIdx.x] + red[3][threadIdx.x];
}

__global__ __launch_bounds__(TPB) void k_reduce(const float* __restrict__ buf,
                                                const float* __restrict__ bl1,
                                                float* __restrict__ out10, int nb) {
    int j = blockIdx.x;
    float s = 0.f;
    for (int k = threadIdx.x; k < nb; k += TPB) s += buf[k * 10 + j];
    int lane = threadIdx.x & 63, wv = threadIdx.x >> 6;
#pragma unroll
    for (int off = 32; off; off >>= 1) s += __shfl_down(s, off);
    __shared__ float red[4];
    if (lane == 0) red[wv] = s;
    __syncthreads();
    if (threadIdx.x == 0) out10[j] = red[0] + red[1] + red[2] + red[3] + bl1[j];
}

__global__ void k_head(const float* __restrict__ out10, const float* __restrict__ Wl2,
                       const float* __restrict__ bl2, float* __restrict__ out) {
    if (threadIdx.x == 0) {
        float t0 = bl2[0], t1 = bl2[1];
#pragma unroll
        for (int j = 0; j < 10; j++) {
            float v = out10[j];
            t0 = fmaf(v, Wl2[j], t0);
            t1 = fmaf(v, Wl2[10 + j], t1);
        }
        out[0] = t0;
        out[1] = t1;
    }
}

static inline int nblk(long n) { return (int)((n + TPB - 1) / TPB); }

extern "C" void kernel_launch(void* const* d_in, const int* in_sizes, int n_in,
                              void* d_out, int out_size, void* d_ws, size_t ws_size,
                              hipStream_t stream) {
    const float* x    = (const float*)d_in[0];
    const float* W1   = (const float*)d_in[1];
    const float* W2   = (const float*)d_in[2];
    const float* W3   = (const float*)d_in[3];
    const float* g1s  = (const float*)d_in[4];
    const float* b1s  = (const float*)d_in[5];
    const float* Wa   = (const float*)d_in[6];
    const float* g2s  = (const float*)d_in[7];
    const float* b2s  = (const float*)d_in[8];
    const float* Wb   = (const float*)d_in[9];
    const float* Ws   = (const float*)d_in[10];
    const float* gf   = (const float*)d_in[11];
    const float* bfv  = (const float*)d_in[12];
    const float* Wc1  = (const float*)d_in[13];
    const float* Wc2  = (const float*)d_in[14];
    const float* g_bn = (const float*)d_in[15];
    const float* b_bn = (const float*)d_in[16];
    const float* Wl1  = (const float*)d_in[17];
    const float* bl1  = (const float*)d_in[18];
    const float* Wl2  = (const float*)d_in[19];
    const float* bl2  = (const float*)d_in[20];
    const int* rb1_in = (const int*)d_in[21];
    const int* rb1_out= (const int*)d_in[22];
    const int* rb1_k  = (const int*)d_in[23];
    const int* rb2_in = (const int*)d_in[24];
    const int* rb2_out= (const int*)d_in[25];
    const int* rb2_k  = (const int*)d_in[26];
    const int* rb3_in = (const int*)d_in[27];
    const int* rb3_out= (const int*)d_in[28];
    const int* rb3_k  = (const int*)d_in[29];
    const int* pseg   = (const int*)d_in[30];
    const int* rb9_in = (const int*)d_in[31];
    const int* rb9_out= (const int*)d_in[32];
    const int* rb9_k  = (const int*)d_in[33];
    const int* px     = (const int*)d_in[34];
    const int* py     = (const int*)d_in[35];
    const int* pz     = (const int*)d_in[36];

    const int N   = in_sizes[0];
    const int P1  = in_sizes[21];
    const int P2  = in_sizes[24];
    const int P3  = in_sizes[27];
    const int P90 = in_sizes[31];
    const int Np  = in_sizes[34];

    // --- workspace carve ---
    char* wsp = (char*)d_ws;
    size_t off = 0;
    auto carve = [&](size_t bytes) -> char* {
        char* p = wsp + off;
        off = (off + bytes + 255) & ~(size_t)255;
        return p;
    };
    float* h1    = (float*)carve((size_t)N * 16 * 4);
    float* h2    = (float*)carve((size_t)N * 16 * 4);
    float* h3    = (float*)carve((size_t)N * 4 * 4);
    float* hpA   = (float*)carve((size_t)Np * 16 * 4);
    float* hpB   = (float*)carve((size_t)Np * 16 * 4);
    float* vbuf  = (float*)carve((size_t)Np * 16 * 4);
    float* wbuf  = (float*)carve((size_t)Np * 16 * 4);
    float* dense = (float*)carve((size_t)16 * PG3 * 4);   // also aliased as c2
    float* c1    = (float*)carve((size_t)16 * DA3 * 4);
    unsigned char* occ  = (unsigned char*)carve(PG3);
    unsigned char* m1   = (unsigned char*)carve((size_t)PG * PG * DB);
    unsigned char* m2   = (unsigned char*)carve((size_t)PG * DB * DB);
    unsigned char* mask = (unsigned char*)carve(DB3);
    float* fbuf  = (float*)carve((size_t)NBF * 10 * 4);
    float* out10 = (float*)carve(10 * 4);
    float* Wp1   = (float*)carve((size_t)432 * 16 * 4);    // conv1 weights [tap][o]
    float* Wp2   = (float*)carve((size_t)2000 * 16 * 4);   // conv2 weights [tap][o]
    float* c2 = dense;  // conv2 output aliases dense (dense dead after conv1)

    // --- zeroing + weight permutes (re-done every call; ws is re-poisoned) ---
    hipMemsetAsync(h1, 0, (size_t)N * 16 * 4, stream);
    hipMemsetAsync(h2, 0, (size_t)N * 16 * 4, stream);
    hipMemsetAsync(h3, 0, (size_t)N * 4 * 4, stream);
    hipMemsetAsync(vbuf, 0, (size_t)Np * 16 * 4, stream);
    hipMemsetAsync(wbuf, 0, (size_t)Np * 16 * 4, stream);
    hipMemsetAsync(dense, 0, (size_t)16 * PG3 * 4, stream);
    hipMemsetAsync(occ, 0, PG3, stream);
    k_hp_init<<<nblk((long)Np * 16), TPB, 0, stream>>>(hpA, Np * 16);
    k_permW<<<nblk(432 * 16), TPB, 0, stream>>>(Wc1, Wp1, 432);
    k_permW<<<nblk(2000 * 16), TPB, 0, stream>>>(Wc2, Wp2, 2000);

    // --- sparse front-end ---
    k_sub1<<<nblk((long)P1 * 16), TPB, 0, stream>>>(x, W1, rb1_in, rb1_out, rb1_k, h1, P1);
    k_sub16<<<nblk((long)P2 * 16), TPB, 0, stream>>>(h1, W2, rb2_in, rb2_out, rb2_k, h2, P2);
    k_sub3<<<nblk((long)P3 * 4), TPB, 0, stream>>>(h2, W3, rb3_in, rb3_out, rb3_k, h3, P3);
    k_pool<<<nblk((long)N * 4), TPB, 0, stream>>>(h3, pseg, hpA, N);

    // --- 6 resnet blocks ---
    float* cur = hpA;
    float* nxt = hpB;
    for (int i = 0; i < 6; i++) {
        const float* WsP = nullptr;
        if (i == 0) WsP = Ws;
        else if (i == 2) WsP = Ws + 256;
        else if (i == 4) WsP = Ws + 512;
        k_sub16bn<<<nblk((long)P90 * 16), TPB, 0, stream>>>(
            cur, g1s + i * 16, b1s + i * 16, Wa + (size_t)i * 6912,
            rb9_in, rb9_out, rb9_k, vbuf, P90);
        k_sub16bn<<<nblk((long)P90 * 16), TPB, 0, stream>>>(
            vbuf, g2s + i * 16, b2s + i * 16, Wb + (size_t)i * 6912,
            rb9_in, rb9_out, rb9_k, wbuf, P90);
        k_resup<<<nblk((long)Np * 16), TPB, 0, stream>>>(cur, wbuf, vbuf, WsP, nxt, Np * 16);
        float* tmp = cur; cur = nxt; nxt = tmp;
    }

    // --- to dense + dense convs ---
    k_scatter<<<nblk((long)Np * 16), TPB, 0, stream>>>(cur, gf, bfv, px, py, pz, dense, occ, Np * 16);
    k_conv1<<<nblk((long)DA2 * C1Z * 2), TPB, 0, stream>>>(dense, Wp1, c1);
    k_conv2<<<nblk((long)DB2 * C2Z * 2), TPB, 0, stream>>>(c1, Wp2, c2);

    // --- mask (separable 7^3 dilation) ---
    k_mask1<<<nblk((long)PG * PG * DB), TPB, 0, stream>>>(occ, m1);
    k_mask2<<<nblk((long)PG * DB * DB), TPB, 0, stream>>>(m1, m2);
    k_mask3<<<nblk(DB3), TPB, 0, stream>>>(m2, mask);

    // --- fused BN/leaky/mask + linear head ---
    k_final<<<NBF, TPB, 0, stream>>>(c2, mask, g_bn, b_bn, Wl1, fbuf);
    k_reduce<<<10, TPB, 0, stream>>>(fbuf, bl1, out10, NBF);
    k_head<<<1, 64, 0, stream>>>(out10, Wl2, bl2, (float*)d_out);
}

// Round 6
// 1589.846 us; speedup vs baseline: 1.1900x; 1.1900x over previous
//
#include <hip/hip_runtime.h>
#include <float.h>

#define TPB 256
#define CTB 128        // conv block size
#define PG 90
#define PG2 8100
#define PG3 729000
#define DA 88
#define DA2 7744
#define DA3 681472
#define DB 84
#define DB2 7056
#define DB3 592704
#define FTOT 9483264   // 16*84^3
#define LEAKC 0.333f
#define NBF 1120       // blocks for final reduction
#define C1ZG 11        // 88/8 z-groups for conv1 (exact)
#define C2ZG 11        // ceil(84/8) z-groups for conv2 (last group 4 valid)
#define NB1H 666       // ceil(DA2*C1ZG/CTB) blocks per oh-half, conv1
#define NB2H 607       // ceil(DB2*C2ZG/CTB) blocks per oh-half, conv2

static __device__ __forceinline__ void atomicMaxF(float* addr, float val) {
    if (val >= 0.f) atomicMax((int*)addr, __float_as_int(val));
    else            atomicMin((unsigned int*)addr, __float_as_uint(val));
}

// hp[Np*16]: channels 0..3 = -FLT_MAX (segment_max identity), 4..15 = 0 (pad)
__global__ void k_hp_init(float* hp, int n16) {
    int t = blockIdx.x * TPB + threadIdx.x;
    if (t < n16) hp[t] = ((t & 15) < 4) ? -FLT_MAX : 0.f;
}

// weight permutes: W[o][tap] -> Wp[tap][o]
__global__ void k_permW(const float* __restrict__ W, float* __restrict__ Wp, int ntap) {
    int t = blockIdx.x * TPB + threadIdx.x;
    if (t >= ntap * 16) return;
    int o = t & 15, tap = t >> 4;
    Wp[t] = W[o * ntap + tap];
}

// subconv f=2: x[N,1] * W1[8,1,16] scatter
__global__ void k_sub1(const float* __restrict__ x, const float* __restrict__ W,
                       const int* __restrict__ rin, const int* __restrict__ rout,
                       const int* __restrict__ rk, float* __restrict__ y, int P) {
    int t = blockIdx.x * TPB + threadIdx.x;
    if (t >= P * 16) return;
    int p = t >> 4, d = t & 15;
    atomicAdd(&y[rout[p] * 16 + d], x[rin[p]] * W[rk[p] * 16 + d]);
}

// generic 16->16 subconv scatter: W[k][c][d]
__global__ void k_sub16(const float* __restrict__ h, const float* __restrict__ W,
                        const int* __restrict__ rin, const int* __restrict__ rout,
                        const int* __restrict__ rk, float* __restrict__ y, int P) {
    int t = blockIdx.x * TPB + threadIdx.x;
    if (t >= P * 16) return;
    int p = t >> 4, d = t & 15;
    const float* hr = h + rin[p] * 16;
    const float* w  = W + rk[p] * 256 + d;
    float acc = 0.f;
#pragma unroll
    for (int c = 0; c < 16; c++) acc = fmaf(hr[c], w[c * 16], acc);
    atomicAdd(&y[rout[p] * 16 + d], acc);
}

// 16->16 subconv with fused BN+ReLU on the input (resnet blocks)
__global__ void k_sub16bn(const float* __restrict__ h, const float* __restrict__ g,
                          const float* __restrict__ b, const float* __restrict__ W,
                          const int* __restrict__ rin, const int* __restrict__ rout,
                          const int* __restrict__ rk, float* __restrict__ y, int P) {
    int t = blockIdx.x * TPB + threadIdx.x;
    if (t >= P * 16) return;
    int p = t >> 4, d = t & 15;
    const float* hr = h + rin[p] * 16;
    const float* w  = W + rk[p] * 256 + d;
    float acc = 0.f;
#pragma unroll
    for (int c = 0; c < 16; c++) {
        float u = fmaxf(fmaf(hr[c], g[c], b[c]), 0.f);
        acc = fmaf(u, w[c * 16], acc);
    }
    atomicAdd(&y[rout[p] * 16 + d], acc);
}

// subconv f=5: 16->4, W3[k][c][d] d<4
__global__ void k_sub3(const float* __restrict__ h, const float* __restrict__ W,
                       const int* __restrict__ rin, const int* __restrict__ rout,
                       const int* __restrict__ rk, float* __restrict__ y, int P) {
    int t = blockIdx.x * TPB + threadIdx.x;
    if (t >= P * 4) return;
    int p = t >> 2, d = t & 3;
    const float* hr = h + rin[p] * 16;
    const float* w  = W + rk[p] * 64 + d;
    float acc = 0.f;
#pragma unroll
    for (int c = 0; c < 16; c++) acc = fmaf(hr[c], w[c * 4], acc);
    atomicAdd(&y[rout[p] * 4 + d], acc);
}

// sparse max-pool: scatter-max h3[N,4] into hp[Np,16] (channels 0..3)
__global__ void k_pool(const float* __restrict__ h3, const int* __restrict__ seg,
                       float* __restrict__ hp, int N) {
    int t = blockIdx.x * TPB + threadIdx.x;
    if (t >= N * 4) return;
    int p = t >> 2, d = t & 3;
    atomicMaxF(&hp[seg[p] * 16 + d], h3[t]);
}

// h_new = w + shortcut(h);  also zero v,w for the next block's scatters
__global__ void k_resup(const float* __restrict__ cur, float* __restrict__ wbuf,
                        float* __restrict__ vbuf, const float* __restrict__ Ws,
                        float* __restrict__ nxt, int n16) {
    int t = blockIdx.x * TPB + threadIdx.x;
    if (t >= n16) return;
    int p = t >> 4, d = t & 15;
    float sc;
    if (Ws != nullptr) {
        const float* row = cur + p * 16;
        float acc = 0.f;
#pragma unroll
        for (int c = 0; c < 16; c++) acc = fmaf(row[c], Ws[c * 16 + d], acc);
        sc = acc;
    } else {
        sc = cur[t];
    }
    nxt[t] = wbuf[t] + sc;
    wbuf[t] = 0.f;
    vbuf[t] = 0.f;
}

// trailing BN+ReLU then scatter to dense grid + occupancy
__global__ void k_scatter(const float* __restrict__ h, const float* __restrict__ gf,
                          const float* __restrict__ bf, const int* __restrict__ px,
                          const int* __restrict__ py, const int* __restrict__ pz,
                          float* __restrict__ dense, unsigned char* __restrict__ occ, int n16) {
    int t = blockIdx.x * TPB + threadIdx.x;
    if (t >= n16) return;
    int p = t >> 4, c = t & 15;
    float v = fmaxf(fmaf(h[t], gf[c], bf[c]), 0.f);
    int pos = (px[p] * PG + py[p]) * PG + pz[p];
    dense[c * PG3 + pos] = v;
    if (c == 0) occ[pos] = 1;
}

// dense conv 3^3, 16->16, 90^3 -> 88^3.
// vz=8 z-block x 8 outs. oh is block-uniform (grid split in halves), so LDS
// staging is race-free and the inner loop is branch-free.
// Per (ci,kd,kh) row: 6 broadcast ds_read_b128 vs 192 FMA -> VALU-bound.
__global__ __launch_bounds__(CTB) void k_conv1(const float* __restrict__ in,
                                               const float* __restrict__ Wp,
                                               float* __restrict__ out) {
    __shared__ float wl[432 * 8];       // [tap][8o] for this block's oh half
    int oh = blockIdx.x >= NB1H ? 1 : 0;
    int idx = (blockIdx.x - oh * NB1H) * CTB + threadIdx.x;
    float4* wl4 = (float4*)wl;
    for (int t = threadIdx.x; t < 432 * 2; t += CTB) {
        int tap = t >> 1, half = t & 1;
        wl4[t] = *(const float4*)(Wp + tap * 16 + oh * 8 + half * 4);
    }
    __syncthreads();
    bool valid = idx < DA2 * C1ZG;
    int ii = valid ? idx : 0;
    int zg = ii % C1ZG;
    int y  = (ii / C1ZG) % DA;
    int x  = ii / (C1ZG * DA);
    int z0 = zg * 8;
    float acc[8][8];
#pragma unroll
    for (int vz = 0; vz < 8; vz++)
#pragma unroll
        for (int o = 0; o < 8; o++) acc[vz][o] = 0.f;
    for (int ci = 0; ci < 16; ci++) {
        const float* ip = in + (size_t)ci * PG3 + x * PG2 + y * PG + z0;
#pragma unroll
        for (int kd = 0; kd < 3; kd++) {
#pragma unroll
            for (int kh = 0; kh < 3; kh++) {
                const float* row = ip + kd * PG2 + kh * PG;
                float4 fa = *(const float4*)row;
                float4 fb = *(const float4*)(row + 4);
                float4 fc = *(const float4*)(row + 8);
                float v[12] = {fa.x, fa.y, fa.z, fa.w, fb.x, fb.y, fb.z, fb.w,
                               fc.x, fc.y, fc.z, fc.w};
                const float* wr = &wl[(ci * 27 + kd * 9 + kh * 3) * 8];
#pragma unroll
                for (int kw = 0; kw < 3; kw++) {
                    const float4* wv = (const float4*)&wr[kw * 8];
                    float4 w0 = wv[0], w1 = wv[1];
#pragma unroll
                    for (int vz = 0; vz < 8; vz++) {
                        float val = v[kw + vz];
                        acc[vz][0] = fmaf(val, w0.x, acc[vz][0]);
                        acc[vz][1] = fmaf(val, w0.y, acc[vz][1]);
                        acc[vz][2] = fmaf(val, w0.z, acc[vz][2]);
                        acc[vz][3] = fmaf(val, w0.w, acc[vz][3]);
                        acc[vz][4] = fmaf(val, w1.x, acc[vz][4]);
                        acc[vz][5] = fmaf(val, w1.y, acc[vz][5]);
                        acc[vz][6] = fmaf(val, w1.z, acc[vz][6]);
                        acc[vz][7] = fmaf(val, w1.w, acc[vz][7]);
                    }
                }
            }
        }
    }
    if (!valid) return;
    int base = x * DA2 + y * DA + z0;
#pragma unroll
    for (int o = 0; o < 8; o++) {
        float* op = out + (size_t)(oh * 8 + o) * DA3 + base;
        float4 s0 = {acc[0][o], acc[1][o], acc[2][o], acc[3][o]};
        float4 s1 = {acc[4][o], acc[5][o], acc[6][o], acc[7][o]};
        *(float4*)op = s0;
        *(float4*)(op + 4) = s1;
    }
}

// dense conv 5^3, 16->16, 88^3 -> 84^3. Same vz=8 x 8-out scheme; weights in
// 4-input-channel LDS chunks (16 KB). oh block-uniform.
__global__ __launch_bounds__(CTB) void k_conv2(const float* __restrict__ in,
                                               const float* __restrict__ Wp,
                                               float* __restrict__ out) {
    __shared__ float wl[4 * 125 * 8];
    int oh = blockIdx.x >= NB2H ? 1 : 0;
    int idx = (blockIdx.x - oh * NB2H) * CTB + threadIdx.x;
    bool valid = idx < DB2 * C2ZG;
    int ii = valid ? idx : 0;
    int zg = ii % C2ZG;
    int y  = (ii / C2ZG) % DB;
    int x  = ii / (C2ZG * DB);
    int z0 = zg * 8;
    float4* wl4 = (float4*)wl;
    float acc[8][8];
#pragma unroll
    for (int vz = 0; vz < 8; vz++)
#pragma unroll
        for (int o = 0; o < 8; o++) acc[vz][o] = 0.f;
    for (int ib = 0; ib < 16; ib += 4) {
        __syncthreads();
        for (int t = threadIdx.x; t < 4 * 125 * 2; t += CTB) {
            int tap = t >> 1, half = t & 1;   // tap = ci_local*125 + tap_local
            wl4[t] = *(const float4*)(Wp + (ib * 125 + tap) * 16 + oh * 8 + half * 4);
        }
        __syncthreads();
#pragma unroll
        for (int ci = 0; ci < 4; ci++) {
            const float* ip = in + (size_t)(ib + ci) * DA3 + x * DA2 + y * DA + z0;
#pragma unroll
            for (int kd = 0; kd < 5; kd++) {
#pragma unroll
                for (int kh = 0; kh < 5; kh++) {
                    const float* row = ip + kd * DA2 + kh * DA;
                    float4 fa = *(const float4*)row;
                    float4 fb = *(const float4*)(row + 4);
                    float4 fc = *(const float4*)(row + 8);
                    float v[12] = {fa.x, fa.y, fa.z, fa.w, fb.x, fb.y, fb.z, fb.w,
                                   fc.x, fc.y, fc.z, fc.w};
                    const float* wr = &wl[(ci * 125 + kd * 25 + kh * 5) * 8];
#pragma unroll
                    for (int kw = 0; kw < 5; kw++) {
                        const float4* wv = (const float4*)&wr[kw * 8];
                        float4 w0 = wv[0], w1 = wv[1];
#pragma unroll
                        for (int vz = 0; vz < 8; vz++) {
                            float val = v[kw + vz];
                            acc[vz][0] = fmaf(val, w0.x, acc[vz][0]);
                            acc[vz][1] = fmaf(val, w0.y, acc[vz][1]);
                            acc[vz][2] = fmaf(val, w0.z, acc[vz][2]);
                            acc[vz][3] = fmaf(val, w0.w, acc[vz][3]);
                            acc[vz][4] = fmaf(val, w1.x, acc[vz][4]);
                            acc[vz][5] = fmaf(val, w1.y, acc[vz][5]);
                            acc[vz][6] = fmaf(val, w1.z, acc[vz][6]);
                            acc[vz][7] = fmaf(val, w1.w, acc[vz][7]);
                        }
                    }
                }
            }
        }
    }
    if (!valid) return;
    int base = x * DB2 + y * DB + z0;
    if (zg < C2ZG - 1) {
#pragma unroll
        for (int o = 0; o < 8; o++) {
            float* op = out + (size_t)(oh * 8 + o) * DB3 + base;
            float4 s0 = {acc[0][o], acc[1][o], acc[2][o], acc[3][o]};
            float4 s1 = {acc[4][o], acc[5][o], acc[6][o], acc[7][o]};
            *(float4*)op = s0;
            *(float4*)(op + 4) = s1;
        }
    } else {  // z0=80: only 4 valid voxels
#pragma unroll
        for (int o = 0; o < 8; o++) {
            float* op = out + (size_t)(oh * 8 + o) * DB3 + base;
            float4 s0 = {acc[0][o], acc[1][o], acc[2][o], acc[3][o]};
            *(float4*)op = s0;
        }
    }
}

// separable 7-wide box dilation of occupancy: z, then y, then x
__global__ void k_mask1(const unsigned char* __restrict__ occ, unsigned char* __restrict__ m1) {
    int t = blockIdx.x * TPB + threadIdx.x;
    if (t >= PG * PG * DB) return;
    int z = t % DB;
    int xy = t / DB;
    const unsigned char* p = occ + xy * PG + z;
    unsigned char m = 0;
#pragma unroll
    for (int k = 0; k < 7; k++) m |= p[k];
    m1[t] = m;
}
__global__ void k_mask2(const unsigned char* __restrict__ m1, unsigned char* __restrict__ m2) {
    int t = blockIdx.x * TPB + threadIdx.x;
    if (t >= PG * DB * DB) return;
    int z = t % DB;
    int y = (t / DB) % DB;
    int x = t / (DB * DB);
    unsigned char m = 0;
#pragma unroll
    for (int k = 0; k < 7; k++) m |= m1[(x * PG + y + k) * DB + z];
    m2[t] = m;
}
__global__ void k_mask3(const unsigned char* __restrict__ m2, unsigned char* __restrict__ mask) {
    int t = blockIdx.x * TPB + threadIdx.x;
    if (t >= DB3) return;
    int z = t % DB;
    int y = (t / DB) % DB;
    int x = t / DB2;
    unsigned char m = 0;
#pragma unroll
    for (int k = 0; k < 7; k++) m |= m2[((x + k) * DB + y) * DB + z];
    mask[t] = m;
}

// fused BN + leaky + mask + 10-way dot with W_lin1 rows; per-block partials to buf
__global__ __launch_bounds__(TPB) void k_final(const float* __restrict__ c2,
                                               const unsigned char* __restrict__ mask,
                                               const float* __restrict__ gbn,
                                               const float* __restrict__ bbn,
                                               const float* __restrict__ Wl1,
                                               float* __restrict__ buf) {
    int tid0 = blockIdx.x * TPB + threadIdx.x;
    int stride = gridDim.x * TPB;
    float part[10];
#pragma unroll
    for (int j = 0; j < 10; j++) part[j] = 0.f;
    for (int c = 0; c < 16; c++) {
        float g = gbn[c], b = bbn[c];
        const float* cc = c2 + (size_t)c * DB3;
        const float* wb = Wl1 + (size_t)c * DB3;
        for (int sp = tid0; sp < DB3; sp += stride) {
            float v = fmaf(cc[sp], g, b);
            v = v > 0.f ? v : LEAKC * v;
            if (mask[sp]) {
#pragma unroll
                for (int j = 0; j < 10; j++)
                    part[j] = fmaf(v, wb[(size_t)j * FTOT + sp], part[j]);
            }
        }
    }
    int lane = threadIdx.x & 63, wv = threadIdx.x >> 6;
    __shared__ float red[4][10];
#pragma unroll
    for (int j = 0; j < 10; j++) {
        float s = part[j];
#pragma unroll
        for (int off = 32; off; off >>= 1) s += __shfl_down(s, off);
        if (lane == 0) red[wv][j] = s;
    }
    __syncthreads();
    if (threadIdx.x < 10)
        buf[blockIdx.x * 10 + threadIdx.x] =
            red[0][threadIdx.x] + red[1][threadIdx.x] + red[2][threadIdx.x] + red[3][threadIdx.x];
}

__global__ __launch_bounds__(TPB) void k_reduce(const float* __restrict__ buf,
                                                const float* __restrict__ bl1,
                                                float* __restrict__ out10, int nb) {
    int j = blockIdx.x;
    float s = 0.f;
    for (int k = threadIdx.x; k < nb; k += TPB) s += buf[k * 10 + j];
    int lane = threadIdx.x & 63, wv = threadIdx.x >> 6;
#pragma unroll
    for (int off = 32; off; off >>= 1) s += __shfl_down(s, off);
    __shared__ float red[4];
    if (lane == 0) red[wv] = s;
    __syncthreads();
    if (threadIdx.x == 0) out10[j] = red[0] + red[1] + red[2] + red[3] + bl1[j];
}

__global__ void k_head(const float* __restrict__ out10, const float* __restrict__ Wl2,
                       const float* __restrict__ bl2, float* __restrict__ out) {
    if (threadIdx.x == 0) {
        float t0 = bl2[0], t1 = bl2[1];
#pragma unroll
        for (int j = 0; j < 10; j++) {
            float v = out10[j];
            t0 = fmaf(v, Wl2[j], t0);
            t1 = fmaf(v, Wl2[10 + j], t1);
        }
        out[0] = t0;
        out[1] = t1;
    }
}

static inline int nblk(long n) { return (int)((n + TPB - 1) / TPB); }

extern "C" void kernel_launch(void* const* d_in, const int* in_sizes, int n_in,
                              void* d_out, int out_size, void* d_ws, size_t ws_size,
                              hipStream_t stream) {
    const float* x    = (const float*)d_in[0];
    const float* W1   = (const float*)d_in[1];
    const float* W2   = (const float*)d_in[2];
    const float* W3   = (const float*)d_in[3];
    const float* g1s  = (const float*)d_in[4];
    const float* b1s  = (const float*)d_in[5];
    const float* Wa   = (const float*)d_in[6];
    const float* g2s  = (const float*)d_in[7];
    const float* b2s  = (const float*)d_in[8];
    const float* Wb   = (const float*)d_in[9];
    const float* Ws   = (const float*)d_in[10];
    const float* gf   = (const float*)d_in[11];
    const float* bfv  = (const float*)d_in[12];
    const float* Wc1  = (const float*)d_in[13];
    const float* Wc2  = (const float*)d_in[14];
    const float* g_bn = (const float*)d_in[15];
    const float* b_bn = (const float*)d_in[16];
    const float* Wl1  = (const float*)d_in[17];
    const float* bl1  = (const float*)d_in[18];
    const float* Wl2  = (const float*)d_in[19];
    const float* bl2  = (const float*)d_in[20];
    const int* rb1_in = (const int*)d_in[21];
    const int* rb1_out= (const int*)d_in[22];
    const int* rb1_k  = (const int*)d_in[23];
    const int* rb2_in = (const int*)d_in[24];
    const int* rb2_out= (const int*)d_in[25];
    const int* rb2_k  = (const int*)d_in[26];
    const int* rb3_in = (const int*)d_in[27];
    const int* rb3_out= (const int*)d_in[28];
    const int* rb3_k  = (const int*)d_in[29];
    const int* pseg   = (const int*)d_in[30];
    const int* rb9_in = (const int*)d_in[31];
    const int* rb9_out= (const int*)d_in[32];
    const int* rb9_k  = (const int*)d_in[33];
    const int* px     = (const int*)d_in[34];
    const int* py     = (const int*)d_in[35];
    const int* pz     = (const int*)d_in[36];

    const int N   = in_sizes[0];
    const int P1  = in_sizes[21];
    const int P2  = in_sizes[24];
    const int P3  = in_sizes[27];
    const int P90 = in_sizes[31];
    const int Np  = in_sizes[34];

    // --- workspace carve ---
    char* wsp = (char*)d_ws;
    size_t off = 0;
    auto carve = [&](size_t bytes) -> char* {
        char* p = wsp + off;
        off = (off + bytes + 255) & ~(size_t)255;
        return p;
    };
    float* h1    = (float*)carve((size_t)N * 16 * 4);
    float* h2    = (float*)carve((size_t)N * 16 * 4);
    float* h3    = (float*)carve((size_t)N * 4 * 4);
    float* hpA   = (float*)carve((size_t)Np * 16 * 4);
    float* hpB   = (float*)carve((size_t)Np * 16 * 4);
    float* vbuf  = (float*)carve((size_t)Np * 16 * 4);
    float* wbuf  = (float*)carve((size_t)Np * 16 * 4);
    float* dense = (float*)carve((size_t)16 * PG3 * 4 + 256);   // +pad for z-overread
    float* c1    = (float*)carve((size_t)16 * DA3 * 4 + 256);   // +pad for z-overread
    unsigned char* occ  = (unsigned char*)carve(PG3);
    unsigned char* m1   = (unsigned char*)carve((size_t)PG * PG * DB);
    unsigned char* m2   = (unsigned char*)carve((size_t)PG * DB * DB);
    unsigned char* mask = (unsigned char*)carve(DB3);
    float* fbuf  = (float*)carve((size_t)NBF * 10 * 4);
    float* out10 = (float*)carve(10 * 4);
    float* Wp1   = (float*)carve((size_t)432 * 16 * 4);    // conv1 weights [tap][o]
    float* Wp2   = (float*)carve((size_t)2000 * 16 * 4);   // conv2 weights [tap][o]
    float* c2 = dense;  // conv2 output aliases dense (dense dead after conv1)

    // --- zeroing + weight permutes ---
    hipMemsetAsync(h1, 0, (size_t)N * 16 * 4, stream);
    hipMemsetAsync(h2, 0, (size_t)N * 16 * 4, stream);
    hipMemsetAsync(h3, 0, (size_t)N * 4 * 4, stream);
    hipMemsetAsync(vbuf, 0, (size_t)Np * 16 * 4, stream);
    hipMemsetAsync(wbuf, 0, (size_t)Np * 16 * 4, stream);
    hipMemsetAsync(dense, 0, (size_t)16 * PG3 * 4, stream);
    hipMemsetAsync(occ, 0, PG3, stream);
    k_hp_init<<<nblk((long)Np * 16), TPB, 0, stream>>>(hpA, Np * 16);
    k_permW<<<nblk(432 * 16), TPB, 0, stream>>>(Wc1, Wp1, 432);
    k_permW<<<nblk(2000 * 16), TPB, 0, stream>>>(Wc2, Wp2, 2000);

    // --- sparse front-end ---
    k_sub1<<<nblk((long)P1 * 16), TPB, 0, stream>>>(x, W1, rb1_in, rb1_out, rb1_k, h1, P1);
    k_sub16<<<nblk((long)P2 * 16), TPB, 0, stream>>>(h1, W2, rb2_in, rb2_out, rb2_k, h2, P2);
    k_sub3<<<nblk((long)P3 * 4), TPB, 0, stream>>>(h2, W3, rb3_in, rb3_out, rb3_k, h3, P3);
    k_pool<<<nblk((long)N * 4), TPB, 0, stream>>>(h3, pseg, hpA, N);

    // --- 6 resnet blocks ---
    float* cur = hpA;
    float* nxt = hpB;
    for (int i = 0; i < 6; i++) {
        const float* WsP = nullptr;
        if (i == 0) WsP = Ws;
        else if (i == 2) WsP = Ws + 256;
        else if (i == 4) WsP = Ws + 512;
        k_sub16bn<<<nblk((long)P90 * 16), TPB, 0, stream>>>(
            cur, g1s + i * 16, b1s + i * 16, Wa + (size_t)i * 6912,
            rb9_in, rb9_out, rb9_k, vbuf, P90);
        k_sub16bn<<<nblk((long)P90 * 16), TPB, 0, stream>>>(
            vbuf, g2s + i * 16, b2s + i * 16, Wb + (size_t)i * 6912,
            rb9_in, rb9_out, rb9_k, wbuf, P90);
        k_resup<<<nblk((long)Np * 16), TPB, 0, stream>>>(cur, wbuf, vbuf, WsP, nxt, Np * 16);
        float* tmp = cur; cur = nxt; nxt = tmp;
    }

    // --- to dense + dense convs ---
    k_scatter<<<nblk((long)Np * 16), TPB, 0, stream>>>(cur, gf, bfv, px, py, pz, dense, occ, Np * 16);
    k_conv1<<<2 * NB1H, CTB, 0, stream>>>(dense, Wp1, c1);
    k_conv2<<<2 * NB2H, CTB, 0, stream>>>(c1, Wp2, c2);

    // --- mask (separable 7^3 dilation) ---
    k_mask1<<<nblk((long)PG * PG * DB), TPB, 0, stream>>>(occ, m1);
    k_mask2<<<nblk((long)PG * DB * DB), TPB, 0, stream>>>(m1, m2);
    k_mask3<<<nblk(DB3), TPB, 0, stream>>>(m2, mask);

    // --- fused BN/leaky/mask + linear head ---
    k_final<<<NBF, TPB, 0, stream>>>(c2, mask, g_bn, b_bn, Wl1, fbuf);
    k_reduce<<<10, TPB, 0, stream>>>(fbuf, bl1, out10, NBF);
    k_head<<<1, 64, 0, stream>>>(out10, Wl2, bl2, (float*)d_out);
}

// Round 9
// 1305.331 us; speedup vs baseline: 1.4494x; 1.2180x over previous
//
#include <hip/hip_runtime.h>
#include <float.h>

#define TPB 256
#define PG 90
#define PG2 8100
#define PG3 729000
#define DA 88
#define DA2 7744
#define DA3 681472
#define DB 84
#define DB2 7056
#define DB3 592704
#define FTOT 9483264   // 16*84^3
#define LEAKC 0.333f
#define NBF 1120       // blocks for final reduction

typedef __attribute__((ext_vector_type(8))) short bf8v;
typedef __attribute__((ext_vector_type(4))) float f4v;

static __device__ __forceinline__ unsigned short f2bf(float f) {
    unsigned int u = __float_as_uint(f);
    unsigned int r = (u + 0x7FFFu + ((u >> 16) & 1u)) >> 16;   // RNE
    return (unsigned short)r;
}
static __device__ __forceinline__ float bf2f(unsigned short h) {
    return __uint_as_float(((unsigned int)h) << 16);
}

static __device__ __forceinline__ void atomicMaxF(float* addr, float val) {
    if (val >= 0.f) atomicMax((int*)addr, __float_as_int(val));
    else            atomicMin((unsigned int*)addr, __float_as_uint(val));
}

// hp[Np*16]: channels 0..3 = -FLT_MAX (segment_max identity), 4..15 = 0 (pad)
__global__ void k_hp_init(float* hp, int n16) {
    int t = blockIdx.x * TPB + threadIdx.x;
    if (t < n16) hp[t] = ((t & 15) < 4) ? -FLT_MAX : 0.f;
}

// Pre-permute conv weights (OIDHW) into MFMA B-fragment order, hi/lo split:
// Wf[(((kd*KH+kh)*NKP+kp)*2+pass)*512 + lane*8 + j]
// k=(lane>>4)*8+j; kwL=k>>4; ci=k&15; o=lane&15; kw=kp*2+kwL (0 if kw>=KW)
__global__ void k_prepW(const float* __restrict__ W, short* __restrict__ Wf,
                        int KD, int KH, int KW, int NKP, int total) {
    int t = blockIdx.x * TPB + threadIdx.x;
    if (t >= total) return;
    int j = t & 7;
    int r = t >> 3;
    int lane = r & 63; r >>= 6;
    int pass = r & 1;  r >>= 1;
    int kp = r % NKP;  r /= NKP;
    int kh = r % KH;
    int kd = r / KH;
    int k  = ((lane >> 4) << 3) + j;
    int kwL = k >> 4, ci = k & 15, o = lane & 15;
    int kw = kp * 2 + kwL;
    float val = 0.f;
    if (kw < KW)
        val = W[((size_t)(o * 16 + ci) * KD + kd) * (KH * KW) + kh * KW + kw];
    unsigned short h = f2bf(val);
    Wf[t] = (pass == 0) ? (short)h : (short)f2bf(val - bf2f(h));
}

// subconv f=2: x[N,1] * W1[8,1,16] scatter
__global__ void k_sub1(const float* __restrict__ x, const float* __restrict__ W,
                       const int* __restrict__ rin, const int* __restrict__ rout,
                       const int* __restrict__ rk, float* __restrict__ y, int P) {
    int t = blockIdx.x * TPB + threadIdx.x;
    if (t >= P * 16) return;
    int p = t >> 4, d = t & 15;
    atomicAdd(&y[rout[p] * 16 + d], x[rin[p]] * W[rk[p] * 16 + d]);
}

// generic 16->16 subconv scatter: W[k][c][d]
__global__ void k_sub16(const float* __restrict__ h, const float* __restrict__ W,
                        const int* __restrict__ rin, const int* __restrict__ rout,
                        const int* __restrict__ rk, float* __restrict__ y, int P) {
    int t = blockIdx.x * TPB + threadIdx.x;
    if (t >= P * 16) return;
    int p = t >> 4, d = t & 15;
    const float* hr = h + rin[p] * 16;
    const float* w  = W + rk[p] * 256 + d;
    float acc = 0.f;
#pragma unroll
    for (int c = 0; c < 16; c++) acc = fmaf(hr[c], w[c * 16], acc);
    atomicAdd(&y[rout[p] * 16 + d], acc);
}

// 16->16 subconv with fused BN+ReLU on the input (resnet blocks)
__global__ void k_sub16bn(const float* __restrict__ h, const float* __restrict__ g,
                          const float* __restrict__ b, const float* __restrict__ W,
                          const int* __restrict__ rin, const int* __restrict__ rout,
                          const int* __restrict__ rk, float* __restrict__ y, int P) {
    int t = blockIdx.x * TPB + threadIdx.x;
    if (t >= P * 16) return;
    int p = t >> 4, d = t & 15;
    const float* hr = h + rin[p] * 16;
    const float* w  = W + rk[p] * 256 + d;
    float acc = 0.f;
#pragma unroll
    for (int c = 0; c < 16; c++) {
        float u = fmaxf(fmaf(hr[c], g[c], b[c]), 0.f);
        acc = fmaf(u, w[c * 16], acc);
    }
    atomicAdd(&y[rout[p] * 16 + d], acc);
}

// subconv f=5: 16->4, W3[k][c][d] d<4
__global__ void k_sub3(const float* __restrict__ h, const float* __restrict__ W,
                       const int* __restrict__ rin, const int* __restrict__ rout,
                       const int* __restrict__ rk, float* __restrict__ y, int P) {
    int t = blockIdx.x * TPB + threadIdx.x;
    if (t >= P * 4) return;
    int p = t >> 2, d = t & 3;
    const float* hr = h + rin[p] * 16;
    const float* w  = W + rk[p] * 64 + d;
    float acc = 0.f;
#pragma unroll
    for (int c = 0; c < 16; c++) acc = fmaf(hr[c], w[c * 4], acc);
    atomicAdd(&y[rout[p] * 4 + d], acc);
}

// sparse max-pool: scatter-max h3[N,4] into hp[Np,16] (channels 0..3)
__global__ void k_pool(const float* __restrict__ h3, const int* __restrict__ seg,
                       float* __restrict__ hp, int N) {
    int t = blockIdx.x * TPB + threadIdx.x;
    if (t >= N * 4) return;
    int p = t >> 2, d = t & 3;
    atomicMaxF(&hp[seg[p] * 16 + d], h3[t]);
}

// h_new = w + shortcut(h);  also zero v,w for the next block's scatters
__global__ void k_resup(const float* __restrict__ cur, float* __restrict__ wbuf,
                        float* __restrict__ vbuf, const float* __restrict__ Ws,
                        float* __restrict__ nxt, int n16) {
    int t = blockIdx.x * TPB + threadIdx.x;
    if (t >= n16) return;
    int p = t >> 4, d = t & 15;
    float sc;
    if (Ws != nullptr) {
        const float* row = cur + p * 16;
        float acc = 0.f;
#pragma unroll
        for (int c = 0; c < 16; c++) acc = fmaf(row[c], Ws[c * 16 + d], acc);
        sc = acc;
    } else {
        sc = cur[t];
    }
    nxt[t] = wbuf[t] + sc;
    wbuf[t] = 0.f;
    vbuf[t] = 0.f;
}

// trailing BN+ReLU then scatter to split-bf16 channel-last dense grid + occupancy
__global__ void k_scatter(const float* __restrict__ h, const float* __restrict__ gf,
                          const float* __restrict__ bf, const int* __restrict__ px,
                          const int* __restrict__ py, const int* __restrict__ pz,
                          short* __restrict__ dsp, unsigned char* __restrict__ occ, int n16) {
    int t = blockIdx.x * TPB + threadIdx.x;
    if (t >= n16) return;
    int p = t >> 4, c = t & 15;
    float v = fmaxf(fmaf(h[t], gf[c], bf[c]), 0.f);
    int pos = (px[p] * PG + py[p]) * PG + pz[p];
    unsigned short hb = f2bf(v);
    dsp[(size_t)pos * 32 + c]      = (short)hb;
    dsp[(size_t)pos * 32 + 16 + c] = (short)f2bf(v - bf2f(hb));
    if (c == 0) occ[pos] = 1;
}

// dense conv 3^3 MFMA: in dsp [PG3][16hi|16lo] bf16, out c1sp [DA3][16hi|16lo] bf16.
// Per block(128thr=2 waves): one (x,y) column. wave0: z-tiles 0-3 (z 0..63),
// wave1: z-tiles 4-5 (z 64..95, stores masked z<88). 3-pass split-bf16.
__global__ __launch_bounds__(128) void k_conv1m(const short* __restrict__ dsp,
                                                const short* __restrict__ Wf,
                                                short* __restrict__ c1sp) {
    int col = blockIdx.x;
    int y = col % DA, x = col / DA;
    int lane = threadIdx.x & 63, wave = threadIdx.x >> 6;
    int v = lane & 15, g = lane >> 4, o = lane & 15;
    int zb = wave * 64;
    int nst = wave ? 2 : 4;
    f4v acc[4];
#pragma unroll
    for (int st = 0; st < 4; st++) acc[st] = 0;
    for (int kd = 0; kd < 3; kd++) {
        for (int kh = 0; kh < 3; kh++) {
            const short* ip = dsp + (size_t)(((x + kd) * PG + (y + kh)) * PG) * 32;
            int fs0 = (kd * 3 + kh) * 2;
#pragma unroll
            for (int kp = 0; kp < 2; kp++) {
                const short* wb = Wf + (size_t)((fs0 + kp) * 2) * 512 + lane * 8;
                bf8v Bh = *(const bf8v*)wb;
                bf8v Bl = *(const bf8v*)(wb + 512);
                const short* ap0 = ip + (size_t)(zb + v + kp * 2 + (g >> 1)) * 32 + (g & 1) * 8;
#pragma unroll
                for (int st = 0; st < 4; st++) {
                    if (st < nst) {
                        const short* ap = ap0 + (size_t)st * 16 * 32;
                        bf8v Ah = *(const bf8v*)ap;
                        bf8v Al = *(const bf8v*)(ap + 16);
                        acc[st] = __builtin_amdgcn_mfma_f32_16x16x32_bf16(Ah, Bh, acc[st], 0, 0, 0);
                        acc[st] = __builtin_amdgcn_mfma_f32_16x16x32_bf16(Al, Bh, acc[st], 0, 0, 0);
                        acc[st] = __builtin_amdgcn_mfma_f32_16x16x32_bf16(Ah, Bl, acc[st], 0, 0, 0);
                    }
                }
            }
        }
    }
    size_t vbase = (size_t)(x * DA + y) * DA;
#pragma unroll
    for (int st = 0; st < 4; st++) {
        if (st < nst) {
#pragma unroll
            for (int r = 0; r < 4; r++) {
                int z = zb + st * 16 + g * 4 + r;   // D row = (lane>>4)*4 + reg
                if (z < DA) {
                    float val = acc[st][r];
                    unsigned short hb = f2bf(val);
                    size_t e = (vbase + z) * 32 + o;
                    c1sp[e]      = (short)hb;
                    c1sp[e + 16] = (short)f2bf(val - bf2f(hb));
                }
            }
        }
    }
}

// dense conv 5^3 MFMA: in c1sp [DA3][16hi|16lo], out c2 fp32 channel-first [16][DB3].
__global__ __launch_bounds__(128) void k_conv2m(const short* __restrict__ c1sp,
                                                const short* __restrict__ Wf,
                                                float* __restrict__ c2) {
    int col = blockIdx.x;
    int y = col % DB, x = col / DB;
    int lane = threadIdx.x & 63, wave = threadIdx.x >> 6;
    int v = lane & 15, g = lane >> 4, o = lane & 15;
    int zb = wave * 64;
    int nst = wave ? 2 : 4;
    f4v acc[4];
#pragma unroll
    for (int st = 0; st < 4; st++) acc[st] = 0;
    for (int kd = 0; kd < 5; kd++) {
        for (int kh = 0; kh < 5; kh++) {
            const short* ip = c1sp + (size_t)(((x + kd) * DA + (y + kh)) * DA) * 32;
            int fs0 = (kd * 5 + kh) * 3;
#pragma unroll
            for (int kp = 0; kp < 3; kp++) {
                const short* wb = Wf + (size_t)((fs0 + kp) * 2) * 512 + lane * 8;
                bf8v Bh = *(const bf8v*)wb;
                bf8v Bl = *(const bf8v*)(wb + 512);
                const short* ap0 = ip + (size_t)(zb + v + kp * 2 + (g >> 1)) * 32 + (g & 1) * 8;
#pragma unroll
                for (int st = 0; st < 4; st++) {
                    if (st < nst) {
                        const short* ap = ap0 + (size_t)st * 16 * 32;
                        bf8v Ah = *(const bf8v*)ap;
                        bf8v Al = *(const bf8v*)(ap + 16);
                        acc[st] = __builtin_amdgcn_mfma_f32_16x16x32_bf16(Ah, Bh, acc[st], 0, 0, 0);
                        acc[st] = __builtin_amdgcn_mfma_f32_16x16x32_bf16(Al, Bh, acc[st], 0, 0, 0);
                        acc[st] = __builtin_amdgcn_mfma_f32_16x16x32_bf16(Ah, Bl, acc[st], 0, 0, 0);
                    }
                }
            }
        }
    }
    int sbase = (x * DB + y) * DB;
#pragma unroll
    for (int st = 0; st < 4; st++) {
        if (st < nst) {
            int z0 = zb + st * 16 + g * 4;
            if (z0 + 3 < DB) {
                f4v s = acc[st];
                *(float4*)(c2 + (size_t)o * DB3 + sbase + z0) =
                    make_float4(s[0], s[1], s[2], s[3]);
            }
        }
    }
}

// separable 7-wide box dilation of occupancy: z, then y, then x
__global__ void k_mask1(const unsigned char* __restrict__ occ, unsigned char* __restrict__ m1) {
    int t = blockIdx.x * TPB + threadIdx.x;
    if (t >= PG * PG * DB) return;
    int z = t % DB;
    int xy = t / DB;
    const unsigned char* p = occ + xy * PG + z;
    unsigned char m = 0;
#pragma unroll
    for (int k = 0; k < 7; k++) m |= p[k];
    m1[t] = m;
}
__global__ void k_mask2(const unsigned char* __restrict__ m1, unsigned char* __restrict__ m2) {
    int t = blockIdx.x * TPB + threadIdx.x;
    if (t >= PG * DB * DB) return;
    int z = t % DB;
    int y = (t / DB) % DB;
    int x = t / (DB * DB);
    unsigned char m = 0;
#pragma unroll
    for (int k = 0; k < 7; k++) m |= m1[(x * PG + y + k) * DB + z];
    m2[t] = m;
}
__global__ void k_mask3(const unsigned char* __restrict__ m2, unsigned char* __restrict__ mask) {
    int t = blockIdx.x * TPB + threadIdx.x;
    if (t >= DB3) return;
    int z = t % DB;
    int y = (t / DB) % DB;
    int x = t / DB2;
    unsigned char m = 0;
#pragma unroll
    for (int k = 0; k < 7; k++) m |= m2[((x + k) * DB + y) * DB + z];
    mask[t] = m;
}

// fused BN + leaky + mask + 10-way dot with W_lin1 rows; per-block partials to buf
__global__ __launch_bounds__(TPB) void k_final(const float* __restrict__ c2,
                                               const unsigned char* __restrict__ mask,
                                               const float* __restrict__ gbn,
                                               const float* __restrict__ bbn,
                                               const float* __restrict__ Wl1,
                                               float* __restrict__ buf) {
    int tid0 = blockIdx.x * TPB + threadIdx.x;
    int stride = gridDim.x * TPB;
    float part[10];
#pragma unroll
    for (int j = 0; j < 10; j++) part[j] = 0.f;
    for (int c = 0; c < 16; c++) {
        float g = gbn[c], b = bbn[c];
        const float* cc = c2 + (size_t)c * DB3;
        const float* wb = Wl1 + (size_t)c * DB3;
        for (int sp = tid0; sp < DB3; sp += stride) {
            float v = fmaf(cc[sp], g, b);
            v = v > 0.f ? v : LEAKC * v;
            if (mask[sp]) {
#pragma unroll
                for (int j = 0; j < 10; j++)
                    part[j] = fmaf(v, wb[(size_t)j * FTOT + sp], part[j]);
            }
        }
    }
    int lane = threadIdx.x & 63, wv = threadIdx.x >> 6;
    __shared__ float red[4][10];
#pragma unroll
    for (int j = 0; j < 10; j++) {
        float s = part[j];
#pragma unroll
        for (int off = 32; off; off >>= 1) s += __shfl_down(s, off);
        if (lane == 0) red[wv][j] = s;
    }
    __syncthreads();
    if (threadIdx.x < 10)
        buf[blockIdx.x * 10 + threadIdx.x] =
            red[0][threadIdx.x] + red[1][threadIdx.x] + red[2][threadIdx.x] + red[3][threadIdx.x];
}

__global__ __launch_bounds__(TPB) void k_reduce(const float* __restrict__ buf,
                                                const float* __restrict__ bl1,
                                                float* __restrict__ out10, int nb) {
    int j = blockIdx.x;
    float s = 0.f;
    for (int k = threadIdx.x; k < nb; k += TPB) s += buf[k * 10 + j];
    int lane = threadIdx.x & 63, wv = threadIdx.x >> 6;
#pragma unroll
    for (int off = 32; off; off >>= 1) s += __shfl_down(s, off);
    __shared__ float red[4];
    if (lane == 0) red[wv] = s;
    __syncthreads();
    if (threadIdx.x == 0) out10[j] = red[0] + red[1] + red[2] + red[3] + bl1[j];
}

__global__ void k_head(const float* __restrict__ out10, const float* __restrict__ Wl2,
                       const float* __restrict__ bl2, float* __restrict__ out) {
    if (threadIdx.x == 0) {
        float t0 = bl2[0], t1 = bl2[1];
#pragma unroll
        for (int j = 0; j < 10; j++) {
            float v = out10[j];
            t0 = fmaf(v, Wl2[j], t0);
            t1 = fmaf(v, Wl2[10 + j], t1);
        }
        out[0] = t0;
        out[1] = t1;
    }
}

static inline int nblk(long n) { return (int)((n + TPB - 1) / TPB); }

extern "C" void kernel_launch(void* const* d_in, const int* in_sizes, int n_in,
                              void* d_out, int out_size, void* d_ws, size_t ws_size,
                              hipStream_t stream) {
    const float* x    = (const float*)d_in[0];
    const float* W1   = (const float*)d_in[1];
    const float* W2   = (const float*)d_in[2];
    const float* W3   = (const float*)d_in[3];
    const float* g1s  = (const float*)d_in[4];
    const float* b1s  = (const float*)d_in[5];
    const float* Wa   = (const float*)d_in[6];
    const float* g2s  = (const float*)d_in[7];
    const float* b2s  = (const float*)d_in[8];
    const float* Wb   = (const float*)d_in[9];
    const float* Ws   = (const float*)d_in[10];
    const float* gf   = (const float*)d_in[11];
    const float* bfv  = (const float*)d_in[12];
    const float* Wc1  = (const float*)d_in[13];
    const float* Wc2  = (const float*)d_in[14];
    const float* g_bn = (const float*)d_in[15];
    const float* b_bn = (const float*)d_in[16];
    const float* Wl1  = (const float*)d_in[17];
    const float* bl1  = (const float*)d_in[18];
    const float* Wl2  = (const float*)d_in[19];
    const float* bl2  = (const float*)d_in[20];
    const int* rb1_in = (const int*)d_in[21];
    const int* rb1_out= (const int*)d_in[22];
    const int* rb1_k  = (const int*)d_in[23];
    const int* rb2_in = (const int*)d_in[24];
    const int* rb2_out= (const int*)d_in[25];
    const int* rb2_k  = (const int*)d_in[26];
    const int* rb3_in = (const int*)d_in[27];
    const int* rb3_out= (const int*)d_in[28];
    const int* rb3_k  = (const int*)d_in[29];
    const int* pseg   = (const int*)d_in[30];
    const int* rb9_in = (const int*)d_in[31];
    const int* rb9_out= (const int*)d_in[32];
    const int* rb9_k  = (const int*)d_in[33];
    const int* px     = (const int*)d_in[34];
    const int* py     = (const int*)d_in[35];
    const int* pz     = (const int*)d_in[36];

    const int N   = in_sizes[0];
    const int P1  = in_sizes[21];
    const int P2  = in_sizes[24];
    const int P3  = in_sizes[27];
    const int P90 = in_sizes[31];
    const int Np  = in_sizes[34];

    // --- workspace carve ---
    char* wsp = (char*)d_ws;
    size_t off = 0;
    auto carve = [&](size_t bytes) -> char* {
        char* p = wsp + off;
        off = (off + bytes + 255) & ~(size_t)255;
        return p;
    };
    float* h1    = (float*)carve((size_t)N * 16 * 4);
    float* h2    = (float*)carve((size_t)N * 16 * 4);
    float* h3    = (float*)carve((size_t)N * 4 * 4);
    float* hpA   = (float*)carve((size_t)Np * 16 * 4);
    float* hpB   = (float*)carve((size_t)Np * 16 * 4);
    float* vbuf  = (float*)carve((size_t)Np * 16 * 4);
    float* wbuf  = (float*)carve((size_t)Np * 16 * 4);
    short* dsp   = (short*)carve((size_t)PG3 * 64 + 1024);  // dense split [PG3][32] bf16 (+OOB pad)
    short* c1sp  = (short*)carve((size_t)DA3 * 64 + 1024);  // conv1 out split [DA3][32] bf16
    unsigned char* occ  = (unsigned char*)carve(PG3);
    unsigned char* m1   = (unsigned char*)carve((size_t)PG * PG * DB);
    unsigned char* m2   = (unsigned char*)carve((size_t)PG * DB * DB);
    unsigned char* mask = (unsigned char*)carve(DB3);
    float* fbuf  = (float*)carve((size_t)NBF * 10 * 4);
    float* out10 = (float*)carve(10 * 4);
    short* Wf1   = (short*)carve((size_t)18432 * 2);   // 9*(kd,kh) x 2kp x 2pass x 512
    short* Wf2   = (short*)carve((size_t)76800 * 2);   // 25 x 3kp x 2pass x 512
    float* c2 = (float*)dsp;  // conv2 fp32 out aliases dsp (dead after conv1m); 37.9MB <= 46.7MB

    // --- zeroing + weight prep ---
    hipMemsetAsync(h1, 0, (size_t)N * 16 * 4, stream);
    hipMemsetAsync(h2, 0, (size_t)N * 16 * 4, stream);
    hipMemsetAsync(h3, 0, (size_t)N * 4 * 4, stream);
    hipMemsetAsync(vbuf, 0, (size_t)Np * 16 * 4, stream);
    hipMemsetAsync(wbuf, 0, (size_t)Np * 16 * 4, stream);
    hipMemsetAsync(dsp, 0, (size_t)PG3 * 64 + 1024, stream);
    hipMemsetAsync(occ, 0, PG3, stream);
    k_hp_init<<<nblk((long)Np * 16), TPB, 0, stream>>>(hpA, Np * 16);
    k_prepW<<<nblk(18432), TPB, 0, stream>>>(Wc1, Wf1, 3, 3, 3, 2, 18432);
    k_prepW<<<nblk(76800), TPB, 0, stream>>>(Wc2, Wf2, 5, 5, 5, 3, 76800);

    // --- sparse front-end ---
    k_sub1<<<nblk((long)P1 * 16), TPB, 0, stream>>>(x, W1, rb1_in, rb1_out, rb1_k, h1, P1);
    k_sub16<<<nblk((long)P2 * 16), TPB, 0, stream>>>(h1, W2, rb2_in, rb2_out, rb2_k, h2, P2);
    k_sub3<<<nblk((long)P3 * 4), TPB, 0, stream>>>(h2, W3, rb3_in, rb3_out, rb3_k, h3, P3);
    k_pool<<<nblk((long)N * 4), TPB, 0, stream>>>(h3, pseg, hpA, N);

    // --- 6 resnet blocks ---
    float* cur = hpA;
    float* nxt = hpB;
    for (int i = 0; i < 6; i++) {
        const float* WsP = nullptr;
        if (i == 0) WsP = Ws;
        else if (i == 2) WsP = Ws + 256;
        else if (i == 4) WsP = Ws + 512;
        k_sub16bn<<<nblk((long)P90 * 16), TPB, 0, stream>>>(
            cur, g1s + i * 16, b1s + i * 16, Wa + (size_t)i * 6912,
            rb9_in, rb9_out, rb9_k, vbuf, P90);
        k_sub16bn<<<nblk((long)P90 * 16), TPB, 0, stream>>>(
            vbuf, g2s + i * 16, b2s + i * 16, Wb + (size_t)i * 6912,
            rb9_in, rb9_out, rb9_k, wbuf, P90);
        k_resup<<<nblk((long)Np * 16), TPB, 0, stream>>>(cur, wbuf, vbuf, WsP, nxt, Np * 16);
        float* tmp = cur; cur = nxt; nxt = tmp;
    }

    // --- to dense (split bf16 channel-last) + MFMA dense convs ---
    k_scatter<<<nblk((long)Np * 16), TPB, 0, stream>>>(cur, gf, bfv, px, py, pz, dsp, occ, Np * 16);
    k_conv1m<<<DA2, 128, 0, stream>>>(dsp, Wf1, c1sp);
    k_conv2m<<<DB2, 128, 0, stream>>>(c1sp, Wf2, c2);

    // --- mask (separable 7^3 dilation) ---
    k_mask1<<<nblk((long)PG * PG * DB), TPB, 0, stream>>>(occ, m1);
    k_mask2<<<nblk((long)PG * DB * DB), TPB, 0, stream>>>(m1, m2);
    k_mask3<<<nblk(DB3), TPB, 0, stream>>>(m2, mask);

    // --- fused BN/leaky/mask + linear head ---
    k_final<<<NBF, TPB, 0, stream>>>(c2, mask, g_bn, b_bn, Wl1, fbuf);
    k_reduce<<<10, TPB, 0, stream>>>(fbuf, bl1, out10, NBF);
    k_head<<<1, 64, 0, stream>>>(out10, Wl2, bl2, (float*)d_out);
}